// Round 5
// baseline (134.074 us; speedup 1.0000x reference)
//
#include <hip/hip_runtime.h>

// x (64,3,512,512) f32, mean_params (64,4) f32.
#define BB 64
#define CC 3
#define HH 512
#define WW 512
#define HW (HH * WW)           // 262144
#define CHW (CC * HW)          // 786432

#define PBX 64                 // max staged patch dim (px)
#define PPAD 65                // padded LDS row stride (odd -> bank spread)

typedef float f2_t __attribute__((ext_vector_type(2), aligned(4)));
typedef float f4_t __attribute__((ext_vector_type(4), aligned(16)));

// Per-batch affine coefficients in PIXEL space: ix = ct*w - st*h + Cx
__global__ __launch_bounds__(64) void prep_kernel(const float* __restrict__ mp,
                                                  float4* __restrict__ cf)
{
    int b = threadIdx.x;
    if (b < BB) {
        float theta = mp[b * 4 + 0];
        float scale = mp[b * 4 + 1];
        float tx    = mp[b * 4 + 2];
        float ty    = mp[b * 4 + 3];
        float s, c;
        sincosf(theta, &s, &c);
        float ct = scale * c;
        float st = scale * s;
        const float d = -255.5f;                 // 256*xs at w=0
        float Cx = d * (ct - st) + 256.0f * tx + 255.5f;
        float Cy = d * (st + ct) + 256.0f * ty + 255.5f;
        cf[b] = make_float4(ct, st, Cx, Cy);
    }
}

// Block = 256 thr -> 32x32 output tile; thread = 1x4 strip; wave = 8x32.
// Scattered bilinear reads go to LDS (staged patch) when the tile's source
// bbox fits 64x64; else fall back to direct global gathers (block-uniform).
__global__ __launch_bounds__(256) void affine_sample_kernel(
    const float* __restrict__ x,
    const float4* __restrict__ cf,
    float* __restrict__ out)
{
    __shared__ float smem[CC][PBX][PPAD];        // 49,920 B -> 3 blocks/CU

    int tid  = threadIdx.x;
    int lane = tid & 63;
    int wid  = tid >> 6;
    int strip = lane & 7;
    int lrow  = lane >> 3;

    int bidx = blockIdx.x;          // 64 batches * 256 tiles
    int b    = bidx >> 8;
    int rem  = bidx & 255;
    int tileH = (rem >> 4) << 5;
    int tileW = (rem & 15) << 5;

    int h  = tileH + (wid << 3) + lrow;
    int w0 = tileW + (strip << 2);

    float4 k = cf[b];
    float ct = k.x, st = k.y, Cx = k.z, Cy = k.w;

    // ---- block-uniform source bbox from tile corners (affine => extremes at corners)
    float wA = (float)tileW, wB = (float)(tileW + 31);
    float hA = (float)tileH, hB = (float)(tileH + 31);
    float cwA = ct * wA, cwB = ct * wB, shA = st * hA, shB = st * hB;
    float ixmin = fminf(cwA, cwB) - fmaxf(shA, shB) + Cx;
    float ixmax = fmaxf(cwA, cwB) - fminf(shA, shB) + Cx;
    float swA = st * wA, swB = st * wB, chA = ct * hA, chB = ct * hB;
    float iymin = fminf(swA, swB) + fminf(chA, chB) + Cy;
    float iymax = fmaxf(swA, swB) + fmaxf(chA, chB) + Cy;

    int bx_lo = (int)floorf(ixmin) - 1;          // -1/+1: ulp-drift safety margin
    int bx_hi = (int)floorf(ixmax) + 2;          // +1 for x1 corner, +1 margin
    int by_lo = (int)floorf(iymin) - 1;
    int by_hi = (int)floorf(iymax) + 2;
    // accessed cols/rows (after clamp) are within [p_lo, p_hi]
    int px_lo = min(max(bx_lo, 0), WW - 2);
    int px_hi = min(max(bx_hi - 1, 0), WW - 2) + 1;
    int py_lo = min(max(by_lo, 0), HH - 2);
    int py_hi = min(max(by_hi - 1, 0), HH - 2) + 1;
    int Bx = px_hi - px_lo + 1;                  // >= 2
    int By = py_hi - py_lo + 1;
    bool staged = (Bx <= PBX) && (By <= PBX);

    if (staged) {
        // coalesced staging: one row per wave-iteration, lane = column
        for (int ch = 0; ch < CC; ++ch) {
            const float* src = x + b * CHW + ch * HW + py_lo * WW + px_lo;
            for (int r = wid; r < By; r += 4) {
                if (lane < Bx) smem[ch][r][lane] = src[r * WW + lane];
            }
        }
        __syncthreads();
    }

    // ---- per-pixel geometry (incremental coords along the 4-px strip)
    float ix = ct * (float)w0 - st * (float)h + Cx;
    float iy = st * (float)w0 + ct * (float)h + Cy;

    float al[4], ar[4], f0[4], f1[4];
    int o0[4], o1[4];
#pragma unroll
    for (int p = 0; p < 4; ++p) {
        float x0f = floorf(ix), y0f = floorf(iy);
        float fx = ix - x0f,    fy = iy - y0f;
        int x0 = (int)x0f, y0 = (int)y0f;
        int y1 = y0 + 1;

        bool xin = (x0 >= 0) & (x0 <= WW - 2);
        float wl = 1.0f - fx;
        al[p] = xin ? wl : ((x0 == -1)     ? fx : 0.0f);
        ar[p] = xin ? fx : ((x0 == WW - 1) ? wl : 0.0f);
        int base = min(max(x0, 0), WW - 2);

        bool vy0 = (y0 >= 0) & (y0 < HH);
        bool vy1 = (y1 >= 0) & (y1 < HH);
        int y0c = min(max(y0, 0), HH - 1);
        int y1c = min(max(y1, 0), HH - 1);
        f0[p] = (1.0f - fy) * (float)vy0;
        f1[p] = fy          * (float)vy1;

        if (staged) {
            int lx = base - px_lo;
            o0[p] = (y0c - py_lo) * PPAD + lx;
            o1[p] = (y1c - py_lo) * PPAD + lx;
        } else {
            o0[p] = y0c * WW + base;
            o1[p] = y1c * WW + base;
        }
        ix += ct;
        iy += st;
    }

    const float* xb = x   + b * CHW;
    float*       ob = out + b * CHW + h * WW + w0;

    if (staged) {
#pragma unroll
        for (int ch = 0; ch < CC; ++ch) {
            const float* pl = &smem[ch][0][0];
            f4_t v;
#pragma unroll
            for (int p = 0; p < 4; ++p) {
                float a0 = pl[o0[p]], a1 = pl[o0[p] + 1];   // ds_read2_b32 pair
                float b0 = pl[o1[p]], b1 = pl[o1[p] + 1];
                v[p] = f0[p] * (al[p] * a0 + ar[p] * a1)
                     + f1[p] * (al[p] * b0 + ar[p] * b1);
            }
            __builtin_nontemporal_store(v, (f4_t*)(ob + ch * HW));
        }
    } else {
#pragma unroll
        for (int ch = 0; ch < CC; ++ch) {
            const float* pl = xb + ch * HW;
            f4_t v;
#pragma unroll
            for (int p = 0; p < 4; ++p) {
                f2_t t = *(const f2_t*)(pl + o0[p]);
                f2_t u = *(const f2_t*)(pl + o1[p]);
                v[p] = f0[p] * (al[p] * t.x + ar[p] * t.y)
                     + f1[p] * (al[p] * u.x + ar[p] * u.y);
            }
            __builtin_nontemporal_store(v, (f4_t*)(ob + ch * HW));
        }
    }
}

extern "C" void kernel_launch(void* const* d_in, const int* in_sizes, int n_in,
                              void* d_out, int out_size, void* d_ws, size_t ws_size,
                              hipStream_t stream)
{
    const float* x  = (const float*)d_in[0];
    const float* mp = (const float*)d_in[1];
    float* out = (float*)d_out;
    float4* cf = (float4*)d_ws;     // 1 KB scratch

    prep_kernel<<<1, 64, 0, stream>>>(mp, cf);
    dim3 block(256);
    dim3 grid(BB * 256);            // 64 batches x 16x16 tiles of 32x32
    affine_sample_kernel<<<grid, block, 0, stream>>>(x, cf, out);
}

// Round 6
// 64.616 us; speedup vs baseline: 2.0749x; 2.0749x over previous
//
#include <hip/hip_runtime.h>

// x (64,3,512,512) f32, mean_params (64,4) f32.
#define BB 64
#define CC 3
#define HH 512
#define WW 512
#define HW (HH * WW)           // 262144
#define CHW (CC * HW)          // 786432

#define PROWS 64               // max staged rows
#define PSTRIDE 68             // LDS row stride in floats; 68 % 32 == 4 -> bank spread

typedef float f2_t __attribute__((ext_vector_type(2), aligned(4)));
typedef float f4_t __attribute__((ext_vector_type(4), aligned(16)));

// Per-batch affine coefficients in PIXEL space: ix = ct*w - st*h + Cx
__global__ __launch_bounds__(64) void prep_kernel(const float* __restrict__ mp,
                                                  float4* __restrict__ cf)
{
    int b = threadIdx.x;
    if (b < BB) {
        float theta = mp[b * 4 + 0];
        float scale = mp[b * 4 + 1];
        float tx    = mp[b * 4 + 2];
        float ty    = mp[b * 4 + 3];
        float s, c;
        sincosf(theta, &s, &c);
        float ct = scale * c;
        float st = scale * s;
        const float d = -255.5f;                 // 256*xs at w=0
        float Cx = d * (ct - st) + 256.0f * tx + 255.5f;
        float Cy = d * (st + ct) + 256.0f * ty + 255.5f;
        cf[b] = make_float4(ct, st, Cx, Cy);
    }
}

// Block = 256 thr -> 32x32 output tile; thread = 1x4 strip; wave = 8x32.
// Staged path: per-channel 64x68 LDS patch, dense f4 staging, scattered reads
// from LDS. Fallback (large |scale|): direct global f2 gathers (R4 path).
__global__ __launch_bounds__(256, 8) void affine_sample_kernel(
    const float* __restrict__ x,
    const float4* __restrict__ cf,
    float* __restrict__ out)
{
    __shared__ float smem[PROWS * PSTRIDE];      // 17408 B -> up to 8 blocks/CU

    int tid  = threadIdx.x;
    int lane = tid & 63;
    int wid  = tid >> 6;
    int strip = lane & 7;
    int lrow  = lane >> 3;

    int bidx = blockIdx.x;          // 64 batches * 256 tiles
    int b    = bidx >> 8;
    int rem  = bidx & 255;
    int tileH = (rem >> 4) << 5;
    int tileW = (rem & 15) << 5;

    int h  = tileH + (wid << 3) + lrow;
    int w0 = tileW + (strip << 2);

    float4 k = cf[b];
    float ct = k.x, st = k.y, Cx = k.z, Cy = k.w;

    // ---- block-uniform source bbox from tile corners
    float wA = (float)tileW, wB = (float)(tileW + 31);
    float hA = (float)tileH, hB = (float)(tileH + 31);
    float cwA = ct * wA, cwB = ct * wB, shA = st * hA, shB = st * hB;
    float ixmin = fminf(cwA, cwB) - fmaxf(shA, shB) + Cx;
    float ixmax = fmaxf(cwA, cwB) - fminf(shA, shB) + Cx;
    float swA = st * wA, swB = st * wB, chA = ct * hA, chB = ct * hB;
    float iymin = fminf(swA, swB) + fminf(chA, chB) + Cy;
    float iymax = fmaxf(swA, swB) + fmaxf(chA, chB) + Cy;

    int bx_lo = (int)floorf(ixmin) - 1;          // +-1: ulp-drift margin
    int bx_hi = (int)floorf(ixmax) + 2;
    int by_lo = (int)floorf(iymin) - 1;
    int by_hi = (int)floorf(iymax) + 2;
    int px_lo = min(max(bx_lo, 0), WW - 2);
    int px_hi = min(max(bx_hi - 1, 0), WW - 2) + 1;
    int py_lo = min(max(by_lo, 0), HH - 2);
    int py_hi = min(max(by_hi - 1, 0), HH - 2) + 1;
    int By = py_hi - py_lo + 1;

    int ax_lo = px_lo & ~3;                      // 16B-aligned window start
    if (ax_lo > WW - 64) ax_lo = WW - 64;        // keep 64-col window in-bounds
    bool staged = ((px_hi - ax_lo) <= 63) && (By <= PROWS);

    // ---- per-pixel geometry (incremental along the 4-px strip)
    float ix = ct * (float)w0 - st * (float)h + Cx;
    float iy = st * (float)w0 + ct * (float)h + Cy;

    float al[4], ar[4], f0[4], f1[4];
    int o0[4], o1[4];
#pragma unroll
    for (int p = 0; p < 4; ++p) {
        float x0f = floorf(ix), y0f = floorf(iy);
        float fx = ix - x0f,    fy = iy - y0f;
        int x0 = (int)x0f, y0 = (int)y0f;
        int y1 = y0 + 1;

        bool xin = (x0 >= 0) & (x0 <= WW - 2);
        float wl = 1.0f - fx;
        al[p] = xin ? wl : ((x0 == -1)     ? fx : 0.0f);
        ar[p] = xin ? fx : ((x0 == WW - 1) ? wl : 0.0f);
        int base = min(max(x0, 0), WW - 2);

        bool vy0 = (y0 >= 0) & (y0 < HH);
        bool vy1 = (y1 >= 0) & (y1 < HH);
        int y0c = min(max(y0, 0), HH - 1);
        int y1c = min(max(y1, 0), HH - 1);
        f0[p] = (1.0f - fy) * (float)vy0;
        f1[p] = fy          * (float)vy1;

        if (staged) {
            int lx = base - ax_lo;               // in [0,62] by construction
            o0[p] = (y0c - py_lo) * PSTRIDE + lx;
            o1[p] = (y1c - py_lo) * PSTRIDE + lx;
        } else {
            o0[p] = y0c * WW + base;
            o1[p] = y1c * WW + base;
        }
        ix += ct;
        iy += st;
    }

    const float* xb = x   + b * CHW;
    float*       ob = out + b * CHW + h * WW + w0;

    if (staged) {
        int r0 = tid >> 4;                       // 0..15
        int c4 = (tid & 15) << 2;                // 0,4,...,60
        const float* srcb = xb + py_lo * WW + ax_lo;
#pragma unroll
        for (int ch = 0; ch < CC; ++ch) {
            if (ch) __syncthreads();             // protect prev channel's reads
            const float* src = srcb + ch * HW;
            for (int r = r0; r < By; r += 16) {  // dense coalesced f4 staging
                f4_t v = *(const f4_t*)(src + r * WW + c4);
                *(f4_t*)(&smem[r * PSTRIDE + c4]) = v;
            }
            __syncthreads();
            f4_t v;
#pragma unroll
            for (int p = 0; p < 4; ++p) {
                float a0 = smem[o0[p]], a1 = smem[o0[p] + 1];
                float b0 = smem[o1[p]], b1 = smem[o1[p] + 1];
                v[p] = f0[p] * (al[p] * a0 + ar[p] * a1)
                     + f1[p] * (al[p] * b0 + ar[p] * b1);
            }
            __builtin_nontemporal_store(v, (f4_t*)(ob + ch * HW));
        }
    } else {
#pragma unroll
        for (int ch = 0; ch < CC; ++ch) {
            const float* pl = xb + ch * HW;
            f4_t v;
#pragma unroll
            for (int p = 0; p < 4; ++p) {
                f2_t t = *(const f2_t*)(pl + o0[p]);
                f2_t u = *(const f2_t*)(pl + o1[p]);
                v[p] = f0[p] * (al[p] * t.x + ar[p] * t.y)
                     + f1[p] * (al[p] * u.x + ar[p] * u.y);
            }
            __builtin_nontemporal_store(v, (f4_t*)(ob + ch * HW));
        }
    }
}

extern "C" void kernel_launch(void* const* d_in, const int* in_sizes, int n_in,
                              void* d_out, int out_size, void* d_ws, size_t ws_size,
                              hipStream_t stream)
{
    const float* x  = (const float*)d_in[0];
    const float* mp = (const float*)d_in[1];
    float* out = (float*)d_out;
    float4* cf = (float4*)d_ws;     // 1 KB scratch

    prep_kernel<<<1, 64, 0, stream>>>(mp, cf);
    dim3 block(256);
    dim3 grid(BB * 256);            // 64 batches x 16x16 tiles of 32x32
    affine_sample_kernel<<<grid, block, 0, stream>>>(x, cf, out);
}